// Round 18
// baseline (469.825 us; speedup 1.0000x reference)
//
#include <hip/hip_runtime.h>
#include <cstdint>
#include <cstddef>

typedef unsigned short u16;
typedef __bf16 bf16_t;
typedef bf16_t bf16x8 __attribute__((ext_vector_type(8)));
typedef float f32x4 __attribute__((ext_vector_type(4)));
typedef unsigned short u16x8 __attribute__((ext_vector_type(8)));

#define DEV __device__ __forceinline__
#define AS1 __attribute__((address_space(1)))
#define AS3 __attribute__((address_space(3)))

DEV u16 f2bf(float f) {
  unsigned u = __float_as_uint(f);
  u += 0x7fffu + ((u >> 16) & 1u);
  return (u16)(u >> 16);
}
DEV float bf2f(u16 h) {
  return __uint_as_float(((unsigned)h) << 16);
}

// ---------------------------------------------------------------- converts
// Fused converts, block-partitioned into two BRANCH-FREE loops so the
// compiler can software-pipeline loads across iterations (r17: the mixed
// per-iteration branch kept it at 2.5 TB/s).  Non-temporal hints on the
// read-once/write-once streams.
//   blocks [0,1024):   weights + gctx (vec8 count 2,359,296 = 9 iters/thr)
//   blocks [1024,4096): acat build    (vec8 count 4,194,304 ~ 5.3 iters/thr)
struct CvtAll {
  const float* s[9];
  u16* d[9];
  long cum8[10];       // cumulative vec8 counts for the 9 jobs
  const float* q;      // queries f32
  const float* it;     // image_tokens f32
  u16* acat;           // 16384 x 2048 bf16
};

__global__ __launch_bounds__(256)
void convert_all(CvtAll j) {
  const int bid = blockIdx.x, tid = threadIdx.x;
  if (bid < 1024) {
    const long w8 = j.cum8[9];
    for (long c = (long)bid * 256 + tid; c < w8; c += 1024l * 256) {
      int jj = 0;
#pragma unroll
      for (int t = 0; t < 8; ++t)
        if (c >= j.cum8[t + 1]) jj = t + 1;      // wave-uniform select chain
      const long e = (c - j.cum8[jj]) * 8;
      const f32x4* src = (const f32x4*)(j.s[jj] + e);
      f32x4 a = __builtin_nontemporal_load(src);
      f32x4 b = __builtin_nontemporal_load(src + 1);
      u16x8 o;
      o[0] = f2bf(a[0]); o[1] = f2bf(a[1]); o[2] = f2bf(a[2]); o[3] = f2bf(a[3]);
      o[4] = f2bf(b[0]); o[5] = f2bf(b[1]); o[6] = f2bf(b[2]); o[7] = f2bf(b[3]);
      __builtin_nontemporal_store(o, (u16x8*)(j.d[jj] + e));
    }
  } else {
    const long a8 = 16384l * 2048 / 8;
    for (long c = (long)(bid - 1024) * 256 + tid; c < a8; c += 3072l * 256) {
      const long e = c * 8;
      const int m = (int)(e >> 11);
      const int k = (int)(e & 2047);
      const float* sp = (k < 1024) ? (j.q + (long)m * 1024 + k)
                                   : (j.it + (long)m * 1024 + (k - 1024));
      const f32x4* src = (const f32x4*)sp;
      f32x4 a = __builtin_nontemporal_load(src);
      f32x4 b = __builtin_nontemporal_load(src + 1);
      u16x8 o;
      o[0] = f2bf(a[0]); o[1] = f2bf(a[1]); o[2] = f2bf(a[2]); o[3] = f2bf(a[3]);
      o[4] = f2bf(b[0]); o[5] = f2bf(b[1]); o[6] = f2bf(b[2]); o[7] = f2bf(b[3]);
      __builtin_nontemporal_store(o, (u16x8*)(j.acat + e));
    }
  }
}

// ---------------------------------------------------------------- layernorm
// bf16 input -> bf16 output (stats in f32)
__global__ __launch_bounds__(256)
void ln_rows_b(const u16* __restrict__ x, const float* __restrict__ g,
               const float* __restrict__ b, u16* __restrict__ out) {
  __shared__ float red[8];
  const int row = blockIdx.x, tid = threadIdx.x;
  const u16* xr = x + (size_t)row * 1024;
  ushort4 hv = *(const ushort4*)(xr + tid * 4);
  float vx = bf2f(hv.x), vy = bf2f(hv.y), vz = bf2f(hv.z), vw = bf2f(hv.w);
  float s = vx + vy + vz + vw;
  float ss = vx * vx + vy * vy + vz * vz + vw * vw;
#pragma unroll
  for (int o = 32; o > 0; o >>= 1) { s += __shfl_xor(s, o); ss += __shfl_xor(ss, o); }
  if ((tid & 63) == 0) { red[tid >> 6] = s; red[4 + (tid >> 6)] = ss; }
  __syncthreads();
  s = red[0] + red[1] + red[2] + red[3];
  ss = red[4] + red[5] + red[6] + red[7];
  const float mean = s * 0.0009765625f;
  const float var = ss * 0.0009765625f - mean * mean;
  const float rinv = rsqrtf(var + 1e-5f);
  const int c = tid * 4;
  float4 gg = *(const float4*)(g + c);
  float4 bb = *(const float4*)(b + c);
  ushort4 o4;
  o4.x = f2bf((vx - mean) * rinv * gg.x + bb.x);
  o4.y = f2bf((vy - mean) * rinv * gg.y + bb.y);
  o4.z = f2bf((vz - mean) * rinv * gg.z + bb.z);
  o4.w = f2bf((vw - mean) * rinv * gg.w + bb.w);
  *(ushort4*)(out + (size_t)row * 1024 + c) = o4;
}

// K/V layernorm with window gather; bf16 input
__global__ __launch_bounds__(256)
void ln_kv(const u16* __restrict__ winp,
           const float* __restrict__ gk, const float* __restrict__ bk,
           const float* __restrict__ gv, const float* __restrict__ bv,
           u16* __restrict__ kout, u16* __restrict__ vout) {
  __shared__ float red[8];
  const int m = blockIdx.x, tid = threadIdx.x;
  const int b = m / 576, rem = m % 576;
  const int qw = rem / 36, w = rem % 36;
  const int gidx = (qw >> 2) * 144 + (w / 6) * 24 + (qw & 3) * 6 + (w % 6);
  const u16* xr = winp + ((size_t)b * 576 + gidx) * 1024;
  ushort4 hv = *(const ushort4*)(xr + tid * 4);
  float vx = bf2f(hv.x), vy = bf2f(hv.y), vz = bf2f(hv.z), vw = bf2f(hv.w);
  float s = vx + vy + vz + vw;
  float ss = vx * vx + vy * vy + vz * vz + vw * vw;
#pragma unroll
  for (int o = 32; o > 0; o >>= 1) { s += __shfl_xor(s, o); ss += __shfl_xor(ss, o); }
  if ((tid & 63) == 0) { red[tid >> 6] = s; red[4 + (tid >> 6)] = ss; }
  __syncthreads();
  s = red[0] + red[1] + red[2] + red[3];
  ss = red[4] + red[5] + red[6] + red[7];
  const float mean = s * 0.0009765625f;
  const float var = ss * 0.0009765625f - mean * mean;
  const float rinv = rsqrtf(var + 1e-5f);
  const int c = tid * 4;
  float4 gg = *(const float4*)(gk + c);
  float4 bb = *(const float4*)(bk + c);
  float4 g2 = *(const float4*)(gv + c);
  float4 b2 = *(const float4*)(bv + c);
  float nx = (vx - mean) * rinv, ny = (vy - mean) * rinv;
  float nz = (vz - mean) * rinv, nw = (vw - mean) * rinv;
  ushort4 ok, ov;
  ok.x = f2bf(nx * gg.x + bb.x); ok.y = f2bf(ny * gg.y + bb.y);
  ok.z = f2bf(nz * gg.z + bb.z); ok.w = f2bf(nw * gg.w + bb.w);
  ov.x = f2bf(nx * g2.x + b2.x); ov.y = f2bf(ny * g2.y + b2.y);
  ov.z = f2bf(nz * g2.z + b2.z); ov.w = f2bf(nw * g2.w + b2.w);
  *(ushort4*)(kout + (size_t)m * 1024 + c) = ok;
  *(ushort4*)(vout + (size_t)m * 1024 + c) = ov;
}

// ---------------------------------------------------------------- GEMM 256x256
// ROUND-13/15/17 BODY WITH PINS, frozen (65 us W_in, MfmaUtil 42%, 0
// conflicts).  r16 A/B proved the sched_barrier/setprio pins load-bearing.
// EPI: 0 bf16, 1 f32, 2 f32 acc+addF(f32), 3 gelu->bf16,
//      5 bf16 acc+addB(bf16, in-place safe per-element)
template <int EPI>
__global__ __launch_bounds__(512, 2)
void gemm256(const u16* __restrict__ A, const u16* __restrict__ Bw,
             u16* __restrict__ outB, float* __restrict__ outF,
             const float* __restrict__ addF, const u16* __restrict__ addB,
             int M, int N, int K) {
  __shared__ __align__(16) u16 lds[2][2][16384];  // [buf][A/B][256 rows x 64 k]
  const int tid = threadIdx.x;
  const int wave = tid >> 6, lane = tid & 63;
  const int fr = lane & 15, fq = lane >> 4;
  const int swz = (blockIdx.x & 7) * ((int)gridDim.x >> 3) + (blockIdx.x >> 3);
  const int brow = (swz >> 2) << 8;   // N=1024 -> 4 col tiles
  const int bcol = (swz & 3) << 8;

  const int srow = tid >> 3;
  const int cgo = ((tid & 7) ^ (srow & 7)) << 3;   // inverse-swizzled global col
  const u16* pa0 = A + (size_t)(brow + srow) * K + cgo;
  const u16* pb0 = Bw + (size_t)(bcol + srow) * K + cgo;
  const size_t rstep = (size_t)64 * K;

  f32x4 acc[8][4];
#pragma unroll
  for (int mf = 0; mf < 8; ++mf)
#pragma unroll
    for (int nf = 0; nf < 4; ++nf) acc[mf][nf] = (f32x4){0.f, 0.f, 0.f, 0.f};

  const int fx = fr & 7;
  const int arow = (wave >> 2) * 128 + fr;
  const int brl = (wave & 3) * 64 + fr;
  const int ck0 = (fq ^ fx) << 3;
  const int ck1 = ((4 + fq) ^ fx) << 3;

  auto STAGE_A = [&](int buf, int kt) {
    const int k0 = kt << 6;
#pragma unroll
    for (int i = 0; i < 4; ++i)
      __builtin_amdgcn_global_load_lds((const AS1 void*)(pa0 + i * rstep + k0),
                                       (AS3 void*)&lds[buf][0][i * 4096 + tid * 8],
                                       16, 0, 0);
  };
  auto STAGE_B = [&](int buf, int kt) {
    const int k0 = kt << 6;
#pragma unroll
    for (int i = 0; i < 4; ++i)
      __builtin_amdgcn_global_load_lds((const AS1 void*)(pb0 + i * rstep + k0),
                                       (AS3 void*)&lds[buf][1][i * 4096 + tid * 8],
                                       16, 0, 0);
  };

  const int NT = K >> 6;
  STAGE_A(0, 0);
  STAGE_B(0, 0);
  __syncthreads();

  bf16x8 a0[4], a1[4], b0[4], b1[4];
  for (int t = 0; t < NT; ++t) {
    const u16* la = &lds[t & 1][0][0];
    const u16* lb = &lds[t & 1][1][0];
    const int nxt = (t + 1) & 1;

#pragma unroll
    for (int nf = 0; nf < 4; ++nf)
      b0[nf] = *(const bf16x8*)&lb[(brl + nf * 16) * 64 + ck0];
#pragma unroll
    for (int mf = 0; mf < 4; ++mf)
      a0[mf] = *(const bf16x8*)&la[(arow + mf * 16) * 64 + ck0];
#pragma unroll
    for (int mf = 0; mf < 4; ++mf)
      a1[mf] = *(const bf16x8*)&la[(arow + 64 + mf * 16) * 64 + ck0];
    if (t + 1 < NT) STAGE_A(nxt, t + 1);
    __builtin_amdgcn_sched_barrier(0);
    __builtin_amdgcn_s_setprio(1);
#pragma unroll
    for (int mf = 0; mf < 4; ++mf)
#pragma unroll
      for (int nf = 0; nf < 4; ++nf)
        acc[mf][nf] = __builtin_amdgcn_mfma_f32_16x16x32_bf16(a0[mf], b0[nf],
                                                              acc[mf][nf], 0, 0, 0);
    __builtin_amdgcn_s_setprio(0);
#pragma unroll
    for (int nf = 0; nf < 4; ++nf)
      b1[nf] = *(const bf16x8*)&lb[(brl + nf * 16) * 64 + ck1];
#pragma unroll
    for (int mf = 0; mf < 4; ++mf)
      a0[mf] = *(const bf16x8*)&la[(arow + mf * 16) * 64 + ck1];
    __builtin_amdgcn_sched_barrier(0);
    __builtin_amdgcn_s_setprio(1);
#pragma unroll
    for (int mf = 0; mf < 4; ++mf)
#pragma unroll
      for (int nf = 0; nf < 4; ++nf)
        acc[4 + mf][nf] = __builtin_amdgcn_mfma_f32_16x16x32_bf16(a1[mf], b0[nf],
                                                                  acc[4 + mf][nf], 0, 0, 0);
    __builtin_amdgcn_s_setprio(0);
#pragma unroll
    for (int mf = 0; mf < 4; ++mf)
      a1[mf] = *(const bf16x8*)&la[(arow + 64 + mf * 16) * 64 + ck1];
    if (t + 1 < NT) STAGE_B(nxt, t + 1);
    __builtin_amdgcn_sched_barrier(0);
    __builtin_amdgcn_s_setprio(1);
#pragma unroll
    for (int mf = 0; mf < 4; ++mf)
#pragma unroll
      for (int nf = 0; nf < 4; ++nf)
        acc[mf][nf] = __builtin_amdgcn_mfma_f32_16x16x32_bf16(a0[mf], b1[nf],
                                                              acc[mf][nf], 0, 0, 0);
    __builtin_amdgcn_s_setprio(0);
    __builtin_amdgcn_sched_barrier(0);
    __builtin_amdgcn_s_setprio(1);
#pragma unroll
    for (int mf = 0; mf < 4; ++mf)
#pragma unroll
      for (int nf = 0; nf < 4; ++nf)
        acc[4 + mf][nf] = __builtin_amdgcn_mfma_f32_16x16x32_bf16(a1[mf], b1[nf],
                                                                  acc[4 + mf][nf], 0, 0, 0);
    __builtin_amdgcn_s_setprio(0);
    __syncthreads();
  }

#pragma unroll
  for (int mf = 0; mf < 8; ++mf) {
    const int row0 = brow + (wave >> 2) * 128 + mf * 16 + fq * 4;
#pragma unroll
    for (int nf = 0; nf < 4; ++nf) {
      const int col = bcol + (wave & 3) * 64 + nf * 16 + fr;
#pragma unroll
      for (int j = 0; j < 4; ++j) {
        const size_t o = (size_t)(row0 + j) * N + col;
        const float vv = acc[mf][nf][j];
        if constexpr (EPI == 0) {
          outB[o] = f2bf(vv);
        } else if constexpr (EPI == 1) {
          outF[o] = vv;
        } else if constexpr (EPI == 2) {
          outF[o] = vv + addF[o];
        } else if constexpr (EPI == 3) {
          outB[o] = f2bf(0.5f * vv * (1.0f + erff(vv * 0.70710678118654752f)));
        } else {
          outB[o] = f2bf(vv + bf2f(addB[o]));  // in-place safe: 1 thread per o
        }
      }
    }
  }
}

// ---------------------------------------------------------------- attention
// MFMA QK^T / wave softmax / swapped PV; V transposed into Vt_lds at staging.
__global__ __launch_bounds__(256)
void attn_kernel(const u16* __restrict__ q, const u16* __restrict__ k,
                 const u16* __restrict__ v, u16* __restrict__ ao) {
  __shared__ __align__(16) u16 Q_lds[64 * 72];
  __shared__ __align__(16) u16 K_lds[48 * 72];
  __shared__ __align__(16) u16 Vt_lds[64 * 72];
  __shared__ __align__(16) u16 P_lds[64 * 72];
  const int bid = blockIdx.x;
  const int h = bid & 15, qw = (bid >> 4) & 15, b = bid >> 8;
  const int tid = threadIdx.x;
  const int wave = tid >> 6, lane = tid & 63;
  const int lq = lane & 15, lk = lane >> 4;

  const size_t qbase = (size_t)b * 1048576 + (size_t)h * 64;
  for (int i = tid; i < 64 * 16; i += 256) {
    const int l = i >> 4, c4 = (i & 15) * 4;
    *(ushort4*)&Q_lds[l * 72 + c4] =
        *(const ushort4*)&q[qbase + (size_t)(l * 16 + qw) * 1024 + c4];
  }
  const size_t kvbase = (size_t)((b * 16 + qw) * 36) * 1024 + (size_t)h * 64;
  for (int i = tid; i < 36 * 16; i += 256) {
    const int w = i >> 4, c4 = (i & 15) * 4;
    *(ushort4*)&K_lds[w * 72 + c4] = *(const ushort4*)&k[kvbase + (size_t)w * 1024 + c4];
    ushort4 vv = *(const ushort4*)&v[kvbase + (size_t)w * 1024 + c4];
    Vt_lds[(c4 + 0) * 72 + w] = vv.x;
    Vt_lds[(c4 + 1) * 72 + w] = vv.y;
    Vt_lds[(c4 + 2) * 72 + w] = vv.z;
    Vt_lds[(c4 + 3) * 72 + w] = vv.w;
  }
  const ushort4 z4 = {0, 0, 0, 0};
  for (int i = tid; i < 64 * 7; i += 256) {     // Vt cols 36..63 = 0
    const int d = i / 7, w = 36 + (i - d * 7) * 4;
    *(ushort4*)&Vt_lds[d * 72 + w] = z4;
  }
  for (int i = tid; i < 64 * 4; i += 256) {     // P cols 48..63 = 0
    const int m = i >> 2, w = 48 + (i & 3) * 4;
    *(ushort4*)&P_lds[m * 72 + w] = z4;
  }
  __syncthreads();

  bf16x8 qa[2];
#pragma unroll
  for (int ks = 0; ks < 2; ++ks)
    qa[ks] = *(const bf16x8*)&Q_lds[(wave * 16 + lq) * 72 + ks * 32 + lk * 8];
  f32x4 accs[3];
#pragma unroll
  for (int nt = 0; nt < 3; ++nt) accs[nt] = (f32x4){0.f, 0.f, 0.f, 0.f};
#pragma unroll
  for (int nt = 0; nt < 3; ++nt)
#pragma unroll
    for (int ks = 0; ks < 2; ++ks) {
      bf16x8 kb = *(const bf16x8*)&K_lds[(nt * 16 + lq) * 72 + ks * 32 + lk * 8];
      accs[nt] = __builtin_amdgcn_mfma_f32_16x16x32_bf16(qa[ks], kb, accs[nt], 0, 0, 0);
    }

  const bool v2ok = (lq < 4);
#pragma unroll
  for (int j = 0; j < 4; ++j) {
    const float s0 = accs[0][j] * 0.125f;
    const float s1 = accs[1][j] * 0.125f;
    const float s2 = v2ok ? accs[2][j] * 0.125f : -1e30f;
    float mx = fmaxf(fmaxf(s0, s1), s2);
    mx = fmaxf(mx, __shfl_xor(mx, 1));
    mx = fmaxf(mx, __shfl_xor(mx, 2));
    mx = fmaxf(mx, __shfl_xor(mx, 4));
    mx = fmaxf(mx, __shfl_xor(mx, 8));
    const float e0 = __expf(s0 - mx);
    const float e1 = __expf(s1 - mx);
    const float e2 = v2ok ? __expf(s2 - mx) : 0.f;
    float sm = e0 + e1 + e2;
    sm += __shfl_xor(sm, 1);
    sm += __shfl_xor(sm, 2);
    sm += __shfl_xor(sm, 4);
    sm += __shfl_xor(sm, 8);
    const float inv = 1.0f / sm;
    const int mrow = wave * 16 + lk * 4 + j;
    P_lds[mrow * 72 + lq] = f2bf(e0 * inv);
    P_lds[mrow * 72 + 16 + lq] = f2bf(e1 * inv);
    P_lds[mrow * 72 + 32 + lq] = f2bf(e2 * inv);
  }
  __syncthreads();

  bf16x8 va[2];
#pragma unroll
  for (int ks = 0; ks < 2; ++ks)
    va[ks] = *(const bf16x8*)&Vt_lds[(wave * 16 + lq) * 72 + ks * 32 + lk * 8];
  f32x4 acco[4];
#pragma unroll
  for (int nt = 0; nt < 4; ++nt) acco[nt] = (f32x4){0.f, 0.f, 0.f, 0.f};
#pragma unroll
  for (int nt = 0; nt < 4; ++nt)
#pragma unroll
    for (int ks = 0; ks < 2; ++ks) {
      bf16x8 pb = *(const bf16x8*)&P_lds[(nt * 16 + lq) * 72 + ks * 32 + lk * 8];
      acco[nt] = __builtin_amdgcn_mfma_f32_16x16x32_bf16(va[ks], pb, acco[nt], 0, 0, 0);
    }

#pragma unroll
  for (int nt = 0; nt < 4; ++nt) {
    const int m = nt * 16 + lq;
    const int d0 = wave * 16 + lk * 4;
    ushort4 ov;
    ov.x = f2bf(acco[nt][0]); ov.y = f2bf(acco[nt][1]);
    ov.z = f2bf(acco[nt][2]); ov.w = f2bf(acco[nt][3]);
    *(ushort4*)&ao[qbase + (size_t)(m * 16 + qw) * 1024 + d0] = ov;
  }
}

// ---------------------------------------------------------------- launch
extern "C" void kernel_launch(void* const* d_in, const int* in_sizes, int n_in,
                              void* d_out, int out_size, void* d_ws, size_t ws_size,
                              hipStream_t stream) {
  const float* gctx = (const float*)d_in[1];
  const float* queries = (const float*)d_in[4];
  const float* image_tokens = (const float*)d_in[5];
  const float* W_in = (const float*)d_in[7];
  const float* W_ctx = (const float*)d_in[8];
  const float* ln_q_g = (const float*)d_in[9];
  const float* ln_q_b = (const float*)d_in[10];
  const float* Wq = (const float*)d_in[11];
  const float* ln_k_g = (const float*)d_in[12];
  const float* ln_k_b = (const float*)d_in[13];
  const float* Wk = (const float*)d_in[14];
  const float* ln_v_g = (const float*)d_in[15];
  const float* ln_v_b = (const float*)d_in[16];
  const float* Wv = (const float*)d_in[17];
  const float* Wo = (const float*)d_in[18];
  const float* norm_g = (const float*)d_in[19];
  const float* norm_b = (const float*)d_in[20];
  const float* W1 = (const float*)d_in[21];
  const float* W2 = (const float*)d_in[22];
  float* out = (float*)d_out;

  // ---- workspace arena (136 MiB) ----
  char* ws = (char*)d_ws;
  const size_t MB = 1024 * 1024;
  u16* w_in_b  = (u16*)(ws + 0 * MB);
  u16* w_ctx_b = (u16*)(ws + 4 * MB);
  u16* wq_b    = (u16*)(ws + 6 * MB);
  u16* wk_b    = (u16*)(ws + 8 * MB);
  u16* wv_b    = (u16*)(ws + 10 * MB);
  u16* wo_b    = (u16*)(ws + 12 * MB);
  u16* w1_b    = (u16*)(ws + 14 * MB);
  u16* w2_b    = (u16*)(ws + 16 * MB);
  char* regA = ws + 18 * MB;   // 64 MiB
  char* regB = regA + 64 * MB; // 36 MiB
  char* regC = regB + 36 * MB; // 18 MiB

  u16* acat = (u16*)regA;
  u16* pqln = (u16*)regA;
  u16* qmat = (u16*)(regA + 32 * MB);
  u16* vln  = (u16*)regA;
  u16* aoh  = (u16*)regA;
  u16* xmat = (u16*)(regA + 32 * MB);

  u16* winp_b = (u16*)regB;             // 9216x1024 bf16
  u16* kmat = (u16*)regB;               // after ln_kv, winp dead
  u16* vmat = (u16*)(regB + 18 * MB);   // V, normal row layout
  u16* gout = (u16*)regB;

  u16* gcb = (u16*)regC;
  u16* kln = (u16*)regC;

  // pq / y live as bf16 in d_out (first 32 MiB); dead before final f32 write
  u16* pq_b = (u16*)d_out;

  CvtAll jobs;
  const float* srcs[9] = {W_in, W_ctx, Wq, Wk, Wv, Wo, W1, W2, gctx};
  u16* dsts[9] = {w_in_b, w_ctx_b, wq_b, wk_b, wv_b, wo_b, w1_b, w2_b, gcb};
  long sizes[9] = {2048l * 1024, 1048576, 1048576, 1048576, 1048576,
                   1048576, 1048576, 1048576, 9216l * 1024};
  long cum = 0;
  for (int j = 0; j < 9; ++j) {
    jobs.s[j] = srcs[j];
    jobs.d[j] = dsts[j];
    jobs.cum8[j] = cum;
    cum += sizes[j] / 8;
  }
  jobs.cum8[9] = cum;
  jobs.q = queries;
  jobs.it = image_tokens;
  jobs.acat = acat;
  convert_all<<<dim3(4096), dim3(256), 0, stream>>>(jobs);

  // grids: M=16384 -> 256 blocks; M=9216 -> 144 blocks (both % 8 == 0)
  gemm256<0><<<dim3(256), dim3(512), 0, stream>>>(acat, w_in_b, pq_b, nullptr,
                                                  nullptr, nullptr, 16384, 1024, 2048);
  ln_rows_b<<<dim3(16384), dim3(256), 0, stream>>>(pq_b, ln_q_g, ln_q_b, pqln);
  gemm256<0><<<dim3(256), dim3(512), 0, stream>>>(pqln, wq_b, qmat, nullptr,
                                                  nullptr, nullptr, 16384, 1024, 1024);
  gemm256<0><<<dim3(144), dim3(512), 0, stream>>>(gcb, w_ctx_b, winp_b, nullptr,
                                                  nullptr, nullptr, 9216, 1024, 1024);
  ln_kv<<<dim3(9216), dim3(256), 0, stream>>>(winp_b, ln_k_g, ln_k_b, ln_v_g,
                                              ln_v_b, kln, vln);
  gemm256<0><<<dim3(144), dim3(512), 0, stream>>>(kln, wk_b, kmat, nullptr,
                                                  nullptr, nullptr, 9216, 1024, 1024);
  gemm256<0><<<dim3(144), dim3(512), 0, stream>>>(vln, wv_b, vmat, nullptr,
                                                  nullptr, nullptr, 9216, 1024, 1024);
  attn_kernel<<<dim3(4096), dim3(256), 0, stream>>>(qmat, kmat, vmat, aoh);
  // y = ao @ Wo^T + pq  (bf16, in-place in d_out)
  gemm256<5><<<dim3(256), dim3(512), 0, stream>>>(aoh, wo_b, pq_b, nullptr,
                                                  nullptr, pq_b, 16384, 1024, 1024);
  ln_rows_b<<<dim3(16384), dim3(256), 0, stream>>>(pq_b, norm_g, norm_b, xmat);
  gemm256<3><<<dim3(256), dim3(512), 0, stream>>>(xmat, w1_b, gout, nullptr,
                                                  nullptr, nullptr, 16384, 1024, 1024);
  // out = h @ W2^T + image_tokens  (f32 -> d_out; y dead by now)
  gemm256<2><<<dim3(256), dim3(512), 0, stream>>>(gout, w2_b, nullptr, out,
                                                  image_tokens, nullptr, 16384, 1024, 1024);
}

// Round 19
// 443.424 us; speedup vs baseline: 1.0595x; 1.0595x over previous
//
#include <hip/hip_runtime.h>
#include <cstdint>
#include <cstddef>

typedef unsigned short u16;
typedef __bf16 bf16_t;
typedef bf16_t bf16x8 __attribute__((ext_vector_type(8)));
typedef float f32x4 __attribute__((ext_vector_type(4)));
typedef unsigned short u16x8 __attribute__((ext_vector_type(8)));

#define DEV __device__ __forceinline__
#define AS1 __attribute__((address_space(1)))
#define AS3 __attribute__((address_space(3)))

DEV u16 f2bf(float f) {
  unsigned u = __float_as_uint(f);
  u += 0x7fffu + ((u >> 16) & 1u);
  return (u16)(u >> 16);
}
DEV float bf2f(u16 h) {
  return __uint_as_float(((unsigned)h) << 16);
}

// ---------------------------------------------------------------- converts
// Branch-free block-partitioned converts (r18 structure, proven: left the
// top-5).  NT hints kept on LOADS (read-once streams) but REMOVED from
// STORES: r18 showed NT stores cost the consuming GEMMs ~2-3 us each
// (produced buffers must stay L2-cacheable for their consumers).
//   blocks [0,1024):   weights + gctx
//   blocks [1024,4096): acat build
struct CvtAll {
  const float* s[9];
  u16* d[9];
  long cum8[10];       // cumulative vec8 counts for the 9 jobs
  const float* q;      // queries f32
  const float* it;     // image_tokens f32
  u16* acat;           // 16384 x 2048 bf16
};

__global__ __launch_bounds__(256)
void convert_all(CvtAll j) {
  const int bid = blockIdx.x, tid = threadIdx.x;
  if (bid < 1024) {
    const long w8 = j.cum8[9];
    for (long c = (long)bid * 256 + tid; c < w8; c += 1024l * 256) {
      int jj = 0;
#pragma unroll
      for (int t = 0; t < 8; ++t)
        if (c >= j.cum8[t + 1]) jj = t + 1;      // wave-uniform select chain
      const long e = (c - j.cum8[jj]) * 8;
      const f32x4* src = (const f32x4*)(j.s[jj] + e);
      f32x4 a = __builtin_nontemporal_load(src);
      f32x4 b = __builtin_nontemporal_load(src + 1);
      u16x8 o;
      o[0] = f2bf(a[0]); o[1] = f2bf(a[1]); o[2] = f2bf(a[2]); o[3] = f2bf(a[3]);
      o[4] = f2bf(b[0]); o[5] = f2bf(b[1]); o[6] = f2bf(b[2]); o[7] = f2bf(b[3]);
      *(u16x8*)(j.d[jj] + e) = o;
    }
  } else {
    const long a8 = 16384l * 2048 / 8;
    for (long c = (long)(bid - 1024) * 256 + tid; c < a8; c += 3072l * 256) {
      const long e = c * 8;
      const int m = (int)(e >> 11);
      const int k = (int)(e & 2047);
      const float* sp = (k < 1024) ? (j.q + (long)m * 1024 + k)
                                   : (j.it + (long)m * 1024 + (k - 1024));
      const f32x4* src = (const f32x4*)sp;
      f32x4 a = __builtin_nontemporal_load(src);
      f32x4 b = __builtin_nontemporal_load(src + 1);
      u16x8 o;
      o[0] = f2bf(a[0]); o[1] = f2bf(a[1]); o[2] = f2bf(a[2]); o[3] = f2bf(a[3]);
      o[4] = f2bf(b[0]); o[5] = f2bf(b[1]); o[6] = f2bf(b[2]); o[7] = f2bf(b[3]);
      *(u16x8*)(j.acat + e) = o;
    }
  }
}

// ---------------------------------------------------------------- layernorm
// bf16 input -> bf16 output (stats in f32)
__global__ __launch_bounds__(256)
void ln_rows_b(const u16* __restrict__ x, const float* __restrict__ g,
               const float* __restrict__ b, u16* __restrict__ out) {
  __shared__ float red[8];
  const int row = blockIdx.x, tid = threadIdx.x;
  const u16* xr = x + (size_t)row * 1024;
  ushort4 hv = *(const ushort4*)(xr + tid * 4);
  float vx = bf2f(hv.x), vy = bf2f(hv.y), vz = bf2f(hv.z), vw = bf2f(hv.w);
  float s = vx + vy + vz + vw;
  float ss = vx * vx + vy * vy + vz * vz + vw * vw;
#pragma unroll
  for (int o = 32; o > 0; o >>= 1) { s += __shfl_xor(s, o); ss += __shfl_xor(ss, o); }
  if ((tid & 63) == 0) { red[tid >> 6] = s; red[4 + (tid >> 6)] = ss; }
  __syncthreads();
  s = red[0] + red[1] + red[2] + red[3];
  ss = red[4] + red[5] + red[6] + red[7];
  const float mean = s * 0.0009765625f;
  const float var = ss * 0.0009765625f - mean * mean;
  const float rinv = rsqrtf(var + 1e-5f);
  const int c = tid * 4;
  float4 gg = *(const float4*)(g + c);
  float4 bb = *(const float4*)(b + c);
  ushort4 o4;
  o4.x = f2bf((vx - mean) * rinv * gg.x + bb.x);
  o4.y = f2bf((vy - mean) * rinv * gg.y + bb.y);
  o4.z = f2bf((vz - mean) * rinv * gg.z + bb.z);
  o4.w = f2bf((vw - mean) * rinv * gg.w + bb.w);
  *(ushort4*)(out + (size_t)row * 1024 + c) = o4;
}

// K/V layernorm with window gather; bf16 input
__global__ __launch_bounds__(256)
void ln_kv(const u16* __restrict__ winp,
           const float* __restrict__ gk, const float* __restrict__ bk,
           const float* __restrict__ gv, const float* __restrict__ bv,
           u16* __restrict__ kout, u16* __restrict__ vout) {
  __shared__ float red[8];
  const int m = blockIdx.x, tid = threadIdx.x;
  const int b = m / 576, rem = m % 576;
  const int qw = rem / 36, w = rem % 36;
  const int gidx = (qw >> 2) * 144 + (w / 6) * 24 + (qw & 3) * 6 + (w % 6);
  const u16* xr = winp + ((size_t)b * 576 + gidx) * 1024;
  ushort4 hv = *(const ushort4*)(xr + tid * 4);
  float vx = bf2f(hv.x), vy = bf2f(hv.y), vz = bf2f(hv.z), vw = bf2f(hv.w);
  float s = vx + vy + vz + vw;
  float ss = vx * vx + vy * vy + vz * vz + vw * vw;
#pragma unroll
  for (int o = 32; o > 0; o >>= 1) { s += __shfl_xor(s, o); ss += __shfl_xor(ss, o); }
  if ((tid & 63) == 0) { red[tid >> 6] = s; red[4 + (tid >> 6)] = ss; }
  __syncthreads();
  s = red[0] + red[1] + red[2] + red[3];
  ss = red[4] + red[5] + red[6] + red[7];
  const float mean = s * 0.0009765625f;
  const float var = ss * 0.0009765625f - mean * mean;
  const float rinv = rsqrtf(var + 1e-5f);
  const int c = tid * 4;
  float4 gg = *(const float4*)(gk + c);
  float4 bb = *(const float4*)(bk + c);
  float4 g2 = *(const float4*)(gv + c);
  float4 b2 = *(const float4*)(bv + c);
  float nx = (vx - mean) * rinv, ny = (vy - mean) * rinv;
  float nz = (vz - mean) * rinv, nw = (vw - mean) * rinv;
  ushort4 ok, ov;
  ok.x = f2bf(nx * gg.x + bb.x); ok.y = f2bf(ny * gg.y + bb.y);
  ok.z = f2bf(nz * gg.z + bb.z); ok.w = f2bf(nw * gg.w + bb.w);
  ov.x = f2bf(nx * g2.x + b2.x); ov.y = f2bf(ny * g2.y + b2.y);
  ov.z = f2bf(nz * g2.z + b2.z); ov.w = f2bf(nw * g2.w + b2.w);
  *(ushort4*)(kout + (size_t)m * 1024 + c) = ok;
  *(ushort4*)(vout + (size_t)m * 1024 + c) = ov;
}

// ---------------------------------------------------------------- GEMM 256x256
// FROZEN round-13/15/17 body with pins (65 us W_in, MfmaUtil 42%, 0
// conflicts; r16 A/B proved the sched_barrier/setprio pins load-bearing).
// EPI: 0 bf16, 1 f32, 2 f32 acc+addF(f32), 3 gelu->bf16,
//      5 bf16 acc+addB(bf16, in-place safe per-element)
template <int EPI>
__global__ __launch_bounds__(512, 2)
void gemm256(const u16* __restrict__ A, const u16* __restrict__ Bw,
             u16* __restrict__ outB, float* __restrict__ outF,
             const float* __restrict__ addF, const u16* __restrict__ addB,
             int M, int N, int K) {
  __shared__ __align__(16) u16 lds[2][2][16384];  // [buf][A/B][256 rows x 64 k]
  const int tid = threadIdx.x;
  const int wave = tid >> 6, lane = tid & 63;
  const int fr = lane & 15, fq = lane >> 4;
  const int swz = (blockIdx.x & 7) * ((int)gridDim.x >> 3) + (blockIdx.x >> 3);
  const int brow = (swz >> 2) << 8;   // N=1024 -> 4 col tiles
  const int bcol = (swz & 3) << 8;

  const int srow = tid >> 3;
  const int cgo = ((tid & 7) ^ (srow & 7)) << 3;   // inverse-swizzled global col
  const u16* pa0 = A + (size_t)(brow + srow) * K + cgo;
  const u16* pb0 = Bw + (size_t)(bcol + srow) * K + cgo;
  const size_t rstep = (size_t)64 * K;

  f32x4 acc[8][4];
#pragma unroll
  for (int mf = 0; mf < 8; ++mf)
#pragma unroll
    for (int nf = 0; nf < 4; ++nf) acc[mf][nf] = (f32x4){0.f, 0.f, 0.f, 0.f};

  const int fx = fr & 7;
  const int arow = (wave >> 2) * 128 + fr;
  const int brl = (wave & 3) * 64 + fr;
  const int ck0 = (fq ^ fx) << 3;
  const int ck1 = ((4 + fq) ^ fx) << 3;

  auto STAGE_A = [&](int buf, int kt) {
    const int k0 = kt << 6;
#pragma unroll
    for (int i = 0; i < 4; ++i)
      __builtin_amdgcn_global_load_lds((const AS1 void*)(pa0 + i * rstep + k0),
                                       (AS3 void*)&lds[buf][0][i * 4096 + tid * 8],
                                       16, 0, 0);
  };
  auto STAGE_B = [&](int buf, int kt) {
    const int k0 = kt << 6;
#pragma unroll
    for (int i = 0; i < 4; ++i)
      __builtin_amdgcn_global_load_lds((const AS1 void*)(pb0 + i * rstep + k0),
                                       (AS3 void*)&lds[buf][1][i * 4096 + tid * 8],
                                       16, 0, 0);
  };

  const int NT = K >> 6;
  STAGE_A(0, 0);
  STAGE_B(0, 0);
  __syncthreads();

  bf16x8 a0[4], a1[4], b0[4], b1[4];
  for (int t = 0; t < NT; ++t) {
    const u16* la = &lds[t & 1][0][0];
    const u16* lb = &lds[t & 1][1][0];
    const int nxt = (t + 1) & 1;

#pragma unroll
    for (int nf = 0; nf < 4; ++nf)
      b0[nf] = *(const bf16x8*)&lb[(brl + nf * 16) * 64 + ck0];
#pragma unroll
    for (int mf = 0; mf < 4; ++mf)
      a0[mf] = *(const bf16x8*)&la[(arow + mf * 16) * 64 + ck0];
#pragma unroll
    for (int mf = 0; mf < 4; ++mf)
      a1[mf] = *(const bf16x8*)&la[(arow + 64 + mf * 16) * 64 + ck0];
    if (t + 1 < NT) STAGE_A(nxt, t + 1);
    __builtin_amdgcn_sched_barrier(0);
    __builtin_amdgcn_s_setprio(1);
#pragma unroll
    for (int mf = 0; mf < 4; ++mf)
#pragma unroll
      for (int nf = 0; nf < 4; ++nf)
        acc[mf][nf] = __builtin_amdgcn_mfma_f32_16x16x32_bf16(a0[mf], b0[nf],
                                                              acc[mf][nf], 0, 0, 0);
    __builtin_amdgcn_s_setprio(0);
#pragma unroll
    for (int nf = 0; nf < 4; ++nf)
      b1[nf] = *(const bf16x8*)&lb[(brl + nf * 16) * 64 + ck1];
#pragma unroll
    for (int mf = 0; mf < 4; ++mf)
      a0[mf] = *(const bf16x8*)&la[(arow + mf * 16) * 64 + ck1];
    __builtin_amdgcn_sched_barrier(0);
    __builtin_amdgcn_s_setprio(1);
#pragma unroll
    for (int mf = 0; mf < 4; ++mf)
#pragma unroll
      for (int nf = 0; nf < 4; ++nf)
        acc[4 + mf][nf] = __builtin_amdgcn_mfma_f32_16x16x32_bf16(a1[mf], b0[nf],
                                                                  acc[4 + mf][nf], 0, 0, 0);
    __builtin_amdgcn_s_setprio(0);
#pragma unroll
    for (int mf = 0; mf < 4; ++mf)
      a1[mf] = *(const bf16x8*)&la[(arow + 64 + mf * 16) * 64 + ck1];
    if (t + 1 < NT) STAGE_B(nxt, t + 1);
    __builtin_amdgcn_sched_barrier(0);
    __builtin_amdgcn_s_setprio(1);
#pragma unroll
    for (int mf = 0; mf < 4; ++mf)
#pragma unroll
      for (int nf = 0; nf < 4; ++nf)
        acc[mf][nf] = __builtin_amdgcn_mfma_f32_16x16x32_bf16(a0[mf], b1[nf],
                                                              acc[mf][nf], 0, 0, 0);
    __builtin_amdgcn_s_setprio(0);
    __builtin_amdgcn_sched_barrier(0);
    __builtin_amdgcn_s_setprio(1);
#pragma unroll
    for (int mf = 0; mf < 4; ++mf)
#pragma unroll
      for (int nf = 0; nf < 4; ++nf)
        acc[4 + mf][nf] = __builtin_amdgcn_mfma_f32_16x16x32_bf16(a1[mf], b1[nf],
                                                                  acc[4 + mf][nf], 0, 0, 0);
    __builtin_amdgcn_s_setprio(0);
    __syncthreads();
  }

#pragma unroll
  for (int mf = 0; mf < 8; ++mf) {
    const int row0 = brow + (wave >> 2) * 128 + mf * 16 + fq * 4;
#pragma unroll
    for (int nf = 0; nf < 4; ++nf) {
      const int col = bcol + (wave & 3) * 64 + nf * 16 + fr;
#pragma unroll
      for (int j = 0; j < 4; ++j) {
        const size_t o = (size_t)(row0 + j) * N + col;
        const float vv = acc[mf][nf][j];
        if constexpr (EPI == 0) {
          outB[o] = f2bf(vv);
        } else if constexpr (EPI == 1) {
          outF[o] = vv;
        } else if constexpr (EPI == 2) {
          outF[o] = vv + addF[o];
        } else if constexpr (EPI == 3) {
          outB[o] = f2bf(0.5f * vv * (1.0f + erff(vv * 0.70710678118654752f)));
        } else {
          outB[o] = f2bf(vv + bf2f(addB[o]));  // in-place safe: 1 thread per o
        }
      }
    }
  }
}

// ---------------------------------------------------------------- attention
// MFMA QK^T / wave softmax / swapped PV; V transposed into Vt_lds at staging.
__global__ __launch_bounds__(256)
void attn_kernel(const u16* __restrict__ q, const u16* __restrict__ k,
                 const u16* __restrict__ v, u16* __restrict__ ao) {
  __shared__ __align__(16) u16 Q_lds[64 * 72];
  __shared__ __align__(16) u16 K_lds[48 * 72];
  __shared__ __align__(16) u16 Vt_lds[64 * 72];
  __shared__ __align__(16) u16 P_lds[64 * 72];
  const int bid = blockIdx.x;
  const int h = bid & 15, qw = (bid >> 4) & 15, b = bid >> 8;
  const int tid = threadIdx.x;
  const int wave = tid >> 6, lane = tid & 63;
  const int lq = lane & 15, lk = lane >> 4;

  const size_t qbase = (size_t)b * 1048576 + (size_t)h * 64;
  for (int i = tid; i < 64 * 16; i += 256) {
    const int l = i >> 4, c4 = (i & 15) * 4;
    *(ushort4*)&Q_lds[l * 72 + c4] =
        *(const ushort4*)&q[qbase + (size_t)(l * 16 + qw) * 1024 + c4];
  }
  const size_t kvbase = (size_t)((b * 16 + qw) * 36) * 1024 + (size_t)h * 64;
  for (int i = tid; i < 36 * 16; i += 256) {
    const int w = i >> 4, c4 = (i & 15) * 4;
    *(ushort4*)&K_lds[w * 72 + c4] = *(const ushort4*)&k[kvbase + (size_t)w * 1024 + c4];
    ushort4 vv = *(const ushort4*)&v[kvbase + (size_t)w * 1024 + c4];
    Vt_lds[(c4 + 0) * 72 + w] = vv.x;
    Vt_lds[(c4 + 1) * 72 + w] = vv.y;
    Vt_lds[(c4 + 2) * 72 + w] = vv.z;
    Vt_lds[(c4 + 3) * 72 + w] = vv.w;
  }
  const ushort4 z4 = {0, 0, 0, 0};
  for (int i = tid; i < 64 * 7; i += 256) {     // Vt cols 36..63 = 0
    const int d = i / 7, w = 36 + (i - d * 7) * 4;
    *(ushort4*)&Vt_lds[d * 72 + w] = z4;
  }
  for (int i = tid; i < 64 * 4; i += 256) {     // P cols 48..63 = 0
    const int m = i >> 2, w = 48 + (i & 3) * 4;
    *(ushort4*)&P_lds[m * 72 + w] = z4;
  }
  __syncthreads();

  bf16x8 qa[2];
#pragma unroll
  for (int ks = 0; ks < 2; ++ks)
    qa[ks] = *(const bf16x8*)&Q_lds[(wave * 16 + lq) * 72 + ks * 32 + lk * 8];
  f32x4 accs[3];
#pragma unroll
  for (int nt = 0; nt < 3; ++nt) accs[nt] = (f32x4){0.f, 0.f, 0.f, 0.f};
#pragma unroll
  for (int nt = 0; nt < 3; ++nt)
#pragma unroll
    for (int ks = 0; ks < 2; ++ks) {
      bf16x8 kb = *(const bf16x8*)&K_lds[(nt * 16 + lq) * 72 + ks * 32 + lk * 8];
      accs[nt] = __builtin_amdgcn_mfma_f32_16x16x32_bf16(qa[ks], kb, accs[nt], 0, 0, 0);
    }

  const bool v2ok = (lq < 4);
#pragma unroll
  for (int j = 0; j < 4; ++j) {
    const float s0 = accs[0][j] * 0.125f;
    const float s1 = accs[1][j] * 0.125f;
    const float s2 = v2ok ? accs[2][j] * 0.125f : -1e30f;
    float mx = fmaxf(fmaxf(s0, s1), s2);
    mx = fmaxf(mx, __shfl_xor(mx, 1));
    mx = fmaxf(mx, __shfl_xor(mx, 2));
    mx = fmaxf(mx, __shfl_xor(mx, 4));
    mx = fmaxf(mx, __shfl_xor(mx, 8));
    const float e0 = __expf(s0 - mx);
    const float e1 = __expf(s1 - mx);
    const float e2 = v2ok ? __expf(s2 - mx) : 0.f;
    float sm = e0 + e1 + e2;
    sm += __shfl_xor(sm, 1);
    sm += __shfl_xor(sm, 2);
    sm += __shfl_xor(sm, 4);
    sm += __shfl_xor(sm, 8);
    const float inv = 1.0f / sm;
    const int mrow = wave * 16 + lk * 4 + j;
    P_lds[mrow * 72 + lq] = f2bf(e0 * inv);
    P_lds[mrow * 72 + 16 + lq] = f2bf(e1 * inv);
    P_lds[mrow * 72 + 32 + lq] = f2bf(e2 * inv);
  }
  __syncthreads();

  bf16x8 va[2];
#pragma unroll
  for (int ks = 0; ks < 2; ++ks)
    va[ks] = *(const bf16x8*)&Vt_lds[(wave * 16 + lq) * 72 + ks * 32 + lk * 8];
  f32x4 acco[4];
#pragma unroll
  for (int nt = 0; nt < 4; ++nt) acco[nt] = (f32x4){0.f, 0.f, 0.f, 0.f};
#pragma unroll
  for (int nt = 0; nt < 4; ++nt)
#pragma unroll
    for (int ks = 0; ks < 2; ++ks) {
      bf16x8 pb = *(const bf16x8*)&P_lds[(nt * 16 + lq) * 72 + ks * 32 + lk * 8];
      acco[nt] = __builtin_amdgcn_mfma_f32_16x16x32_bf16(va[ks], pb, acco[nt], 0, 0, 0);
    }

#pragma unroll
  for (int nt = 0; nt < 4; ++nt) {
    const int m = nt * 16 + lq;
    const int d0 = wave * 16 + lk * 4;
    ushort4 ov;
    ov.x = f2bf(acco[nt][0]); ov.y = f2bf(acco[nt][1]);
    ov.z = f2bf(acco[nt][2]); ov.w = f2bf(acco[nt][3]);
    *(ushort4*)&ao[qbase + (size_t)(m * 16 + qw) * 1024 + d0] = ov;
  }
}

// ---------------------------------------------------------------- launch
extern "C" void kernel_launch(void* const* d_in, const int* in_sizes, int n_in,
                              void* d_out, int out_size, void* d_ws, size_t ws_size,
                              hipStream_t stream) {
  const float* gctx = (const float*)d_in[1];
  const float* queries = (const float*)d_in[4];
  const float* image_tokens = (const float*)d_in[5];
  const float* W_in = (const float*)d_in[7];
  const float* W_ctx = (const float*)d_in[8];
  const float* ln_q_g = (const float*)d_in[9];
  const float* ln_q_b = (const float*)d_in[10];
  const float* Wq = (const float*)d_in[11];
  const float* ln_k_g = (const float*)d_in[12];
  const float* ln_k_b = (const float*)d_in[13];
  const float* Wk = (const float*)d_in[14];
  const float* ln_v_g = (const float*)d_in[15];
  const float* ln_v_b = (const float*)d_in[16];
  const float* Wv = (const float*)d_in[17];
  const float* Wo = (const float*)d_in[18];
  const float* norm_g = (const float*)d_in[19];
  const float* norm_b = (const float*)d_in[20];
  const float* W1 = (const float*)d_in[21];
  const float* W2 = (const float*)d_in[22];
  float* out = (float*)d_out;

  // ---- workspace arena (136 MiB) ----
  char* ws = (char*)d_ws;
  const size_t MB = 1024 * 1024;
  u16* w_in_b  = (u16*)(ws + 0 * MB);
  u16* w_ctx_b = (u16*)(ws + 4 * MB);
  u16* wq_b    = (u16*)(ws + 6 * MB);
  u16* wk_b    = (u16*)(ws + 8 * MB);
  u16* wv_b    = (u16*)(ws + 10 * MB);
  u16* wo_b    = (u16*)(ws + 12 * MB);
  u16* w1_b    = (u16*)(ws + 14 * MB);
  u16* w2_b    = (u16*)(ws + 16 * MB);
  char* regA = ws + 18 * MB;   // 64 MiB
  char* regB = regA + 64 * MB; // 36 MiB
  char* regC = regB + 36 * MB; // 18 MiB

  u16* acat = (u16*)regA;
  u16* pqln = (u16*)regA;
  u16* qmat = (u16*)(regA + 32 * MB);
  u16* vln  = (u16*)regA;
  u16* aoh  = (u16*)regA;
  u16* xmat = (u16*)(regA + 32 * MB);

  u16* winp_b = (u16*)regB;             // 9216x1024 bf16
  u16* kmat = (u16*)regB;               // after ln_kv, winp dead
  u16* vmat = (u16*)(regB + 18 * MB);   // V, normal row layout
  u16* gout = (u16*)regB;

  u16* gcb = (u16*)regC;
  u16* kln = (u16*)regC;

  // pq / y live as bf16 in d_out (first 32 MiB); dead before final f32 write
  u16* pq_b = (u16*)d_out;

  CvtAll jobs;
  const float* srcs[9] = {W_in, W_ctx, Wq, Wk, Wv, Wo, W1, W2, gctx};
  u16* dsts[9] = {w_in_b, w_ctx_b, wq_b, wk_b, wv_b, wo_b, w1_b, w2_b, gcb};
  long sizes[9] = {2048l * 1024, 1048576, 1048576, 1048576, 1048576,
                   1048576, 1048576, 1048576, 9216l * 1024};
  long cum = 0;
  for (int j = 0; j < 9; ++j) {
    jobs.s[j] = srcs[j];
    jobs.d[j] = dsts[j];
    jobs.cum8[j] = cum;
    cum += sizes[j] / 8;
  }
  jobs.cum8[9] = cum;
  jobs.q = queries;
  jobs.it = image_tokens;
  jobs.acat = acat;
  convert_all<<<dim3(4096), dim3(256), 0, stream>>>(jobs);

  // grids: M=16384 -> 256 blocks; M=9216 -> 144 blocks (both % 8 == 0)
  gemm256<0><<<dim3(256), dim3(512), 0, stream>>>(acat, w_in_b, pq_b, nullptr,
                                                  nullptr, nullptr, 16384, 1024, 2048);
  ln_rows_b<<<dim3(16384), dim3(256), 0, stream>>>(pq_b, ln_q_g, ln_q_b, pqln);
  gemm256<0><<<dim3(256), dim3(512), 0, stream>>>(pqln, wq_b, qmat, nullptr,
                                                  nullptr, nullptr, 16384, 1024, 1024);
  gemm256<0><<<dim3(144), dim3(512), 0, stream>>>(gcb, w_ctx_b, winp_b, nullptr,
                                                  nullptr, nullptr, 9216, 1024, 1024);
  ln_kv<<<dim3(9216), dim3(256), 0, stream>>>(winp_b, ln_k_g, ln_k_b, ln_v_g,
                                              ln_v_b, kln, vln);
  gemm256<0><<<dim3(144), dim3(512), 0, stream>>>(kln, wk_b, kmat, nullptr,
                                                  nullptr, nullptr, 9216, 1024, 1024);
  gemm256<0><<<dim3(144), dim3(512), 0, stream>>>(vln, wv_b, vmat, nullptr,
                                                  nullptr, nullptr, 9216, 1024, 1024);
  attn_kernel<<<dim3(4096), dim3(256), 0, stream>>>(qmat, kmat, vmat, aoh);
  // y = ao @ Wo^T + pq  (bf16, in-place in d_out)
  gemm256<5><<<dim3(256), dim3(512), 0, stream>>>(aoh, wo_b, pq_b, nullptr,
                                                  nullptr, pq_b, 16384, 1024, 1024);
  ln_rows_b<<<dim3(16384), dim3(256), 0, stream>>>(pq_b, norm_g, norm_b, xmat);
  gemm256<3><<<dim3(256), dim3(512), 0, stream>>>(xmat, w1_b, gout, nullptr,
                                                  nullptr, nullptr, 16384, 1024, 1024);
  // out = h @ W2^T + image_tokens  (f32 -> d_out; y dead by now)
  gemm256<2><<<dim3(256), dim3(512), 0, stream>>>(gout, w2_b, nullptr, out,
                                                  image_tokens, nullptr, 16384, 1024, 1024);
}